// Round 1
// baseline (67.330 us; speedup 1.0000x reference)
//
#include <hip/hip_runtime.h>

// Problem: state[2, 4096, 512] f32; apply 4 CNOT permutation matrices along the
// middle axis. Composition: out[n,i,b] = in[n, q(i), b] with
// q(i) = p1(p2(p3(p4(i)))) — last gate's perm applied to the output index first.
// Pairs (control,target) as qubits, bit pos = 11 - qubit:
//   p1=(0,1):  ctrl bit 11, tgt bit 10
//   p2=(2,3):  ctrl bit 9,  tgt bit 8
//   p3=(5,2):  ctrl bit 6,  tgt bit 9
//   p4=(11,7): ctrl bit 0,  tgt bit 4

__device__ __forceinline__ int cnot_perm(int i) {
    int j = i;
    j ^= (j & 1) << 4;           // p4: if bit0 set, flip bit4
    j ^= ((j >> 6) & 1) << 9;    // p3: if bit6 set, flip bit9
    j ^= ((j >> 9) & 1) << 8;    // p2: if bit9 set, flip bit8  (sees p3's update)
    j ^= ((j >> 11) & 1) << 10;  // p1: if bit11 set, flip bit10
    return j;
}

// One thread per float4 (4 batch elements). Row = (n*4096 + i), 128 float4/row.
__global__ void __launch_bounds__(256)
CNOT_layer_16140487098686_kernel(const float4* __restrict__ in,
                                 float4* __restrict__ out) {
    int tid = blockIdx.x * blockDim.x + threadIdx.x;   // 0 .. 2*4096*128-1
    int off = tid & 127;      // float4 index within the 512-wide batch row
    int row = tid >> 7;       // 0 .. 8191
    int n   = row >> 12;      // block index (0/1)
    int i   = row & 4095;     // output middle index
    int j   = cnot_perm(i);   // source middle index
    out[tid] = in[(((n << 12) | j) << 7) | off];
}

extern "C" void kernel_launch(void* const* d_in, const int* in_sizes, int n_in,
                              void* d_out, int out_size, void* d_ws, size_t ws_size,
                              hipStream_t stream) {
    const float4* in = (const float4*)d_in[0];
    float4* out = (float4*)d_out;
    // total float4 elements = 2*4096*512/4 = 1,048,576
    const int total = 2 * 4096 * (512 / 4);
    CNOT_layer_16140487098686_kernel<<<total / 256, 256, 0, stream>>>(in, out);
}

// Round 2
// 66.652 us; speedup vs baseline: 1.0102x; 1.0102x over previous
//
#include <hip/hip_runtime.h>

// state[2, 4096, 512] f32; out[n,i,b] = in[n, q(i), b] where q composes the 4
// CNOT permutations (last gate applied to the output index first).
// Pure row-permutation copy: each middle-index row is a contiguous 2 KiB blob.
//   p4=(11,7): if bit0 set flip bit4
//   p3=(5,2):  if bit6 set flip bit9
//   p2=(2,3):  if bit9 set flip bit8   (sees p3's update)
//   p1=(0,1):  if bit11 set flip bit10

__device__ __forceinline__ int cnot_perm(int i) {
    int j = i;
    j ^= (j & 1) << 4;
    j ^= ((j >> 6) & 1) << 9;
    j ^= ((j >> 9) & 1) << 8;
    j ^= ((j >> 11) & 1) << 10;
    return j;
}

// Two float4 per thread: thread t handles float4 indices {t, t + TOTAL/2}.
// Each half is a fully-coalesced row-permuted copy; one perm calc per half.
__global__ void __launch_bounds__(256)
CNOT_layer_16140487098686_kernel(const float4* __restrict__ in,
                                 float4* __restrict__ out) {
    const int HALF = 2 * 4096 * 128 / 2;   // 524288 float4 per half
    int tid = blockIdx.x * blockDim.x + threadIdx.x;

    #pragma unroll
    for (int h = 0; h < 2; ++h) {
        int t   = tid + h * HALF;
        int off = t & 127;       // float4 index within 512-float batch row
        int row = t >> 7;        // 0 .. 8191 (n*4096 + i)
        int n   = row >> 12;
        int i   = row & 4095;
        int j   = cnot_perm(i);
        out[t] = in[(((n << 12) | j) << 7) | off];
    }
}

extern "C" void kernel_launch(void* const* d_in, const int* in_sizes, int n_in,
                              void* d_out, int out_size, void* d_ws, size_t ws_size,
                              hipStream_t stream) {
    const float4* in = (const float4*)d_in[0];
    float4* out = (float4*)d_out;
    const int threads = 2 * 4096 * 128 / 2;   // half the float4 count
    CNOT_layer_16140487098686_kernel<<<threads / 256, 256, 0, stream>>>(in, out);
}